// Round 3
// baseline (752.944 us; speedup 1.0000x reference)
//
#include <hip/hip_runtime.h>
#include <hip/hip_fp16.h>
#include <stdint.h>

#define PLANE_HALVES (512u * 512u * 32u)   // 8388608 halves = 16 MB per plane

typedef _Float16 f16x8 __attribute__((ext_vector_type(8)));
typedef float    f32x4 __attribute__((ext_vector_type(4)));

union F16x8U { f16x8 v; uint4 u; };

// ---------------- transpose planes [C=32][512][512] f32 -> [512][512][32] f16 ----
__global__ __launch_bounds__(256) void tp_planes(
    const float* __restrict__ pxy,
    const float* __restrict__ pyz,
    const float* __restrict__ pxz,
    __half* __restrict__ ws)
{
    unsigned bid = blockIdx.x;          // 3 * 512 * 2 = 3072 blocks
    unsigned hb = bid & 1u;             // x half
    unsigned y  = (bid >> 1) & 511u;
    unsigned p  = bid >> 10;            // 0..2
    const float* __restrict__ src = (p == 0) ? pxy : (p == 1) ? pyz : pxz;
    unsigned t  = threadIdx.x;
    unsigned cg = t & 3u;               // channel group of 8
    unsigned xq = t >> 2;               // 0..63
    unsigned x  = hb * 256u + xq * 4u;
    unsigned c0 = cg * 8u;
    float4 v[8];
#pragma unroll
    for (int i = 0; i < 8; ++i)
        v[i] = *reinterpret_cast<const float4*>(
            src + (size_t)(c0 + i) * 262144u + y * 512u + x);
#pragma unroll
    for (int j = 0; j < 4; ++j) {
        __half2 h[4];
#pragma unroll
        for (int i = 0; i < 4; ++i) {
            float a = reinterpret_cast<const float*>(&v[2 * i])[j];
            float b = reinterpret_cast<const float*>(&v[2 * i + 1])[j];
            h[i] = __floats2half2_rn(a, b);
        }
        __half* dst = ws + (size_t)p * PLANE_HALVES +
                      (size_t)(y * 512u + x + j) * 32u + c0;
        *reinterpret_cast<uint4*>(dst) = *reinterpret_cast<const uint4*>(h);
    }
}

// ---------------- transpose lines [C=32][512][1] f32 -> [512][32] f32 ------------
__global__ __launch_bounds__(256) void tp_lines(
    const float* __restrict__ lx, const float* __restrict__ ly,
    const float* __restrict__ lz, float* __restrict__ wl)
{
    int e = blockIdx.x * 256 + threadIdx.x;   // 3*512*32 = 49152
    int l = e >> 14;
    int r = e & 16383;
    int h = r >> 5;
    int c = r & 31;
    const float* src = (l == 0) ? lx : (l == 1) ? ly : lz;
    wl[e] = src[c * 512 + h];
}

// ---------------- pack W1 [32][128] f32 into MFMA B-fragments f16 ----------------
// layout: [tile t=0..7][lane L=0..63][j=0..7], elem = W1[k=(L>>4)*8+j][n=t*16+(L&15)]
__global__ __launch_bounds__(256) void pack_w1(
    const float* __restrict__ W1, __half* __restrict__ w)
{
    int tid = blockIdx.x * 256 + threadIdx.x;   // 512 total
    if (tid >= 512) return;
    int t = tid >> 6, L = tid & 63;
    int n  = t * 16 + (L & 15);
    int kg = L >> 4;
    __half h[8];
#pragma unroll
    for (int j = 0; j < 8; ++j)
        h[j] = __float2half(W1[(kg * 8 + j) * 128 + n]);
    *reinterpret_cast<uint4*>(w + tid * 8) = *reinterpret_cast<const uint4*>(h);
}

// ---------------- fused sample + MFMA MLP ----------------------------------------
struct LI { int i0, i1; float w0, w1; };

__device__ inline LI mk(float g) {
    float t = (g + 1.0f) * 0.5f * 511.0f;
    float f = floorf(t);
    LI r;
    r.w1 = t - f;
    r.w0 = 1.0f - r.w1;
    int i0 = (int)f;
    i0 = i0 < 0 ? 0 : (i0 > 511 ? 511 : i0);
    r.i0 = i0;
    r.i1 = i0 < 511 ? i0 + 1 : 511;   // if i1 clamped, w1==0 -> matches zero-pad
    return r;
}

__device__ inline void load8h(const __half* __restrict__ p, float o[8]) {
    uint4 u = *reinterpret_cast<const uint4*>(p);
    __half2 h0 = *reinterpret_cast<__half2*>(&u.x);
    __half2 h1 = *reinterpret_cast<__half2*>(&u.y);
    __half2 h2 = *reinterpret_cast<__half2*>(&u.z);
    __half2 h3 = *reinterpret_cast<__half2*>(&u.w);
    float2 f0 = __half22float2(h0), f1 = __half22float2(h1);
    float2 f2 = __half22float2(h2), f3 = __half22float2(h3);
    o[0] = f0.x; o[1] = f0.y; o[2] = f1.x; o[3] = f1.y;
    o[4] = f2.x; o[5] = f2.y; o[6] = f3.x; o[7] = f3.y;
}

__device__ inline void bilerp8(const __half* __restrict__ plane,
                               const LI& Hi, const LI& Wi, int c0, float o[8]) {
    float w00 = Hi.w0 * Wi.w0, w01 = Hi.w0 * Wi.w1;
    float w10 = Hi.w1 * Wi.w0, w11 = Hi.w1 * Wi.w1;
    const __half* b00 = plane + ((size_t)(Hi.i0 * 512 + Wi.i0) * 32 + c0);
    const __half* b01 = plane + ((size_t)(Hi.i0 * 512 + Wi.i1) * 32 + c0);
    const __half* b10 = plane + ((size_t)(Hi.i1 * 512 + Wi.i0) * 32 + c0);
    const __half* b11 = plane + ((size_t)(Hi.i1 * 512 + Wi.i1) * 32 + c0);
    float v00[8], v01[8], v10[8], v11[8];
    load8h(b00, v00); load8h(b01, v01); load8h(b10, v10); load8h(b11, v11);
#pragma unroll
    for (int i = 0; i < 8; ++i)
        o[i] = v00[i] * w00 + v01[i] * w01 + v10[i] * w10 + v11[i] * w11;
}

__device__ inline void lerp8(const float* __restrict__ line,
                             const LI& L, int c0, float o[8]) {
    const float4* a = reinterpret_cast<const float4*>(line + L.i0 * 32 + c0);
    const float4* b = reinterpret_cast<const float4*>(line + L.i1 * 32 + c0);
    float4 a0 = a[0], a1 = a[1], b0 = b[0], b1 = b[1];
    o[0] = a0.x * L.w0 + b0.x * L.w1;
    o[1] = a0.y * L.w0 + b0.y * L.w1;
    o[2] = a0.z * L.w0 + b0.z * L.w1;
    o[3] = a0.w * L.w0 + b0.w * L.w1;
    o[4] = a1.x * L.w0 + b1.x * L.w1;
    o[5] = a1.y * L.w0 + b1.y * L.w1;
    o[6] = a1.z * L.w0 + b1.z * L.w1;
    o[7] = a1.w * L.w0 + b1.w * L.w1;
}

// LDS feature staging: per wave 64 rows x 40 halves (80B stride -> 2-way banks max)
#define FROW 40

__global__ __launch_bounds__(256, 4) void tensorf_fused(
    const float* __restrict__ coords,
    const __half* __restrict__ wsp,
    const float* __restrict__ wsl,
    const __half* __restrict__ wsw1,    // [8][64][8] f16 B-fragments
    const float* __restrict__ b1,
    const float* __restrict__ W2,
    const float* __restrict__ b2,
    float* __restrict__ out, int P)
{
    __shared__ __align__(16) __half sfeat[4 * 64 * FROW];   // 20480 B
    int tid  = threadIdx.x;
    int wave = tid >> 6, lane = tid & 63;
    int pbase = blockIdx.x * 256 + wave * 64;
    int p  = pbase + lane;
    int pc = p < P ? p : P - 1;

    float x = coords[3 * pc + 0];
    float y = coords[3 * pc + 1];
    float z = coords[3 * pc + 2];
    LI ax = mk(x), ay = mk(y), az = mk(z);
    const __half* pXY = wsp;                  // H from y, W from x
    const __half* pYZ = wsp + 8388608u;       // H from z, W from y
    const __half* pXZ = wsp + 16777216u;      // H from z, W from x
    const float* lX = wsl;
    const float* lY = wsl + 16384;
    const float* lZ = wsl + 32768;

#pragma unroll
    for (int ch = 0; ch < 4; ++ch) {
        int c0 = ch * 8;
        float pv[8], lv[8], f8[8];
        // features = x_embed*yz + y_embed*xz + z_embed*xy
        bilerp8(pYZ, az, ay, c0, pv);
        lerp8(lX, ax, c0, lv);
#pragma unroll
        for (int i = 0; i < 8; ++i) f8[i] = lv[i] * pv[i];

        bilerp8(pXZ, az, ax, c0, pv);
        lerp8(lY, ay, c0, lv);
#pragma unroll
        for (int i = 0; i < 8; ++i) f8[i] = fmaf(lv[i], pv[i], f8[i]);

        bilerp8(pXY, ay, ax, c0, pv);
        lerp8(lZ, az, c0, lv);
#pragma unroll
        for (int i = 0; i < 8; ++i) f8[i] = fmaf(lv[i], pv[i], f8[i]);

        F16x8U fu;
#pragma unroll
        for (int i = 0; i < 8; ++i) fu.v[i] = (_Float16)f8[i];
        *reinterpret_cast<uint4*>(sfeat + tid * FROW + c0) = fu.u;
    }
    __syncthreads();

    // B fragments (W1), all 8 N-tiles
    f16x8 Bf[8];
#pragma unroll
    for (int t = 0; t < 8; ++t)
        Bf[t] = *reinterpret_cast<const f16x8*>(wsw1 + (t * 64 + lane) * 8);

    // A fragments: 4 M-tiles of this wave's 64 points
    const __half* wb = sfeat + wave * 64 * FROW;
    f16x8 Af[4];
#pragma unroll
    for (int m = 0; m < 4; ++m)
        Af[m] = *reinterpret_cast<const f16x8*>(
            wb + (m * 16 + (lane & 15)) * FROW + (lane >> 4) * 8);

    int nlane = lane & 15;
    f32x4 part[4];
#pragma unroll
    for (int m = 0; m < 4; ++m) part[m] = (f32x4)0.f;

#pragma unroll
    for (int t = 0; t < 8; ++t) {
        float bb  = b1[t * 16 + nlane];
        float w2t = W2[t * 16 + nlane];
        f32x4 cin = { bb, bb, bb, bb };
#pragma unroll
        for (int m = 0; m < 4; ++m) {
            f32x4 acc = __builtin_amdgcn_mfma_f32_16x16x32_f16(Af[m], Bf[t], cin, 0, 0, 0);
#pragma unroll
            for (int r = 0; r < 4; ++r) {
                float h = fmaxf(acc[r], 0.f);
                part[m][r] = fmaf(h, w2t, part[m][r]);
            }
        }
    }

    // reduce across the 16 lanes of each row group (xor 1,2,4,8)
#pragma unroll
    for (int mask = 1; mask < 16; mask <<= 1) {
#pragma unroll
        for (int m = 0; m < 4; ++m) {
#pragma unroll
            for (int r = 0; r < 4; ++r)
                part[m][r] += __shfl_xor(part[m][r], mask, 64);
        }
    }

    // write: row = m*16 + (lane>>4)*4 + r ; lanes nlane<4 write element r=nlane
    float b2v = b2[0];
    if (nlane < 4) {
        int g = lane >> 4;
#pragma unroll
        for (int m = 0; m < 4; ++m) {
            float v = (nlane == 0) ? part[m][0] :
                      (nlane == 1) ? part[m][1] :
                      (nlane == 2) ? part[m][2] : part[m][3];
            int op = pbase + m * 16 + g * 4 + nlane;
            if (op < P) out[op] = v + b2v;
        }
    }
}

extern "C" void kernel_launch(void* const* d_in, const int* in_sizes, int n_in,
                              void* d_out, int out_size, void* d_ws, size_t ws_size,
                              hipStream_t stream)
{
    const float* coords   = (const float*)d_in[0];
    const float* line_x   = (const float*)d_in[1];
    const float* line_y   = (const float*)d_in[2];
    const float* line_z   = (const float*)d_in[3];
    const float* plane_xy = (const float*)d_in[4];
    const float* plane_yz = (const float*)d_in[5];
    const float* plane_xz = (const float*)d_in[6];
    const float* W1 = (const float*)d_in[7];
    const float* b1 = (const float*)d_in[8];
    const float* W2 = (const float*)d_in[9];
    const float* b2 = (const float*)d_in[10];
    int P = in_sizes[0] / 3;

    const size_t off_lines = 3ull * PLANE_HALVES * 2ull;             // 50331648
    const size_t off_w1    = off_lines + 3ull * 512ull * 32ull * 4ull;
    const size_t need      = off_w1 + 8ull * 64ull * 8ull * 2ull;    // +8 KB

    if (ws_size < need) return;

    __half* wsp  = (__half*)d_ws;
    float*  wsl  = (float*)((char*)d_ws + off_lines);
    __half* wsw1 = (__half*)((char*)d_ws + off_w1);

    tp_planes<<<3072, 256, 0, stream>>>(plane_xy, plane_yz, plane_xz, wsp);
    tp_lines<<<192, 256, 0, stream>>>(line_x, line_y, line_z, wsl);
    pack_w1<<<2, 256, 0, stream>>>(W1, wsw1);

    int grid = (P + 255) / 256;
    tensorf_fused<<<grid, 256, 0, stream>>>(coords, wsp, wsl, wsw1,
                                            b1, W2, b2, (float*)d_out, P);
}

// Round 4
// 532.235 us; speedup vs baseline: 1.4147x; 1.4147x over previous
//
#include <hip/hip_runtime.h>
#include <hip/hip_fp16.h>
#include <stdint.h>

#define PLANE_HALVES (512u * 512u * 32u)   // 8388608 halves = 16 MB per plane

typedef _Float16 f16x8 __attribute__((ext_vector_type(8)));
typedef float    f32x4 __attribute__((ext_vector_type(4)));

union F16x8U { f16x8 v; uint4 u; };

// ---------------- transpose planes [C=32][512][512] f32 -> [512][512][32] f16 ----
__global__ __launch_bounds__(256) void tp_planes(
    const float* __restrict__ pxy,
    const float* __restrict__ pyz,
    const float* __restrict__ pxz,
    __half* __restrict__ ws)
{
    unsigned bid = blockIdx.x;          // 3 * 512 * 2 = 3072 blocks
    unsigned hb = bid & 1u;             // x half
    unsigned y  = (bid >> 1) & 511u;
    unsigned p  = bid >> 10;            // 0..2
    const float* __restrict__ src = (p == 0) ? pxy : (p == 1) ? pyz : pxz;
    unsigned t  = threadIdx.x;
    unsigned cg = t & 3u;               // channel group of 8
    unsigned xq = t >> 2;               // 0..63
    unsigned x  = hb * 256u + xq * 4u;
    unsigned c0 = cg * 8u;
    float4 v[8];
#pragma unroll
    for (int i = 0; i < 8; ++i)
        v[i] = *reinterpret_cast<const float4*>(
            src + (size_t)(c0 + i) * 262144u + y * 512u + x);
#pragma unroll
    for (int j = 0; j < 4; ++j) {
        __half2 h[4];
#pragma unroll
        for (int i = 0; i < 4; ++i) {
            float a = reinterpret_cast<const float*>(&v[2 * i])[j];
            float b = reinterpret_cast<const float*>(&v[2 * i + 1])[j];
            h[i] = __floats2half2_rn(a, b);
        }
        __half* dst = ws + (size_t)p * PLANE_HALVES +
                      (size_t)(y * 512u + x + j) * 32u + c0;
        *reinterpret_cast<uint4*>(dst) = *reinterpret_cast<const uint4*>(h);
    }
}

// ---------------- transpose lines [C=32][512][1] f32 -> [512][32] f32 ------------
__global__ __launch_bounds__(256) void tp_lines(
    const float* __restrict__ lx, const float* __restrict__ ly,
    const float* __restrict__ lz, float* __restrict__ wl)
{
    int e = blockIdx.x * 256 + threadIdx.x;   // 3*512*32 = 49152
    int l = e >> 14;
    int r = e & 16383;
    int h = r >> 5;
    int c = r & 31;
    const float* src = (l == 0) ? lx : (l == 1) ? ly : lz;
    wl[e] = src[c * 512 + h];
}

// ---------------- pack W1 [32][128] f32 into MFMA B-fragments f16 ----------------
// layout: [tile t=0..7][lane L=0..63][j=0..7], elem = W1[k=(L>>4)*8+j][n=t*16+(L&15)]
__global__ __launch_bounds__(256) void pack_w1(
    const float* __restrict__ W1, __half* __restrict__ w)
{
    int tid = blockIdx.x * 256 + threadIdx.x;   // 512 total
    if (tid >= 512) return;
    int t = tid >> 6, L = tid & 63;
    int n  = t * 16 + (L & 15);
    int kg = L >> 4;
    __half h[8];
#pragma unroll
    for (int j = 0; j < 8; ++j)
        h[j] = __float2half(W1[(kg * 8 + j) * 128 + n]);
    *reinterpret_cast<uint4*>(w + tid * 8) = *reinterpret_cast<const uint4*>(h);
}

// ---------------- fused sample + MFMA MLP ----------------------------------------
struct LI { int i0, i1; float w0, w1; };

__device__ inline LI mk(float g) {
    float t = (g + 1.0f) * 0.5f * 511.0f;
    float f = floorf(t);
    LI r;
    r.w1 = t - f;
    r.w0 = 1.0f - r.w1;
    int i0 = (int)f;
    i0 = i0 < 0 ? 0 : (i0 > 511 ? 511 : i0);
    r.i0 = i0;
    r.i1 = i0 < 511 ? i0 + 1 : 511;   // if i1 clamped, w1==0 -> matches zero-pad
    return r;
}

__device__ inline void unpack8(const uint4& u, float o[8]) {
    __half2 h0 = *reinterpret_cast<const __half2*>(&u.x);
    __half2 h1 = *reinterpret_cast<const __half2*>(&u.y);
    __half2 h2 = *reinterpret_cast<const __half2*>(&u.z);
    __half2 h3 = *reinterpret_cast<const __half2*>(&u.w);
    float2 f0 = __half22float2(h0), f1 = __half22float2(h1);
    float2 f2 = __half22float2(h2), f3 = __half22float2(h3);
    o[0] = f0.x; o[1] = f0.y; o[2] = f1.x; o[3] = f1.y;
    o[4] = f2.x; o[5] = f2.y; o[6] = f3.x; o[7] = f3.y;
}

// One plane: fetch 4 full 64B corner lines, lerp all 32 channels,
// feat[c] += linevals[c] * bilerp[c].  line is [512][32] f32 (L1/L2-hot).
__device__ inline void plane_acc(const __half* __restrict__ plane,
                                 const LI& Hi, const LI& Wi,
                                 const float* __restrict__ line, const LI& L,
                                 float feat[32]) {
    float w00 = Hi.w0 * Wi.w0, w01 = Hi.w0 * Wi.w1;
    float w10 = Hi.w1 * Wi.w0, w11 = Hi.w1 * Wi.w1;
    const uint4* p00 = reinterpret_cast<const uint4*>(plane + (size_t)(Hi.i0 * 512 + Wi.i0) * 32);
    const uint4* p01 = reinterpret_cast<const uint4*>(plane + (size_t)(Hi.i0 * 512 + Wi.i1) * 32);
    const uint4* p10 = reinterpret_cast<const uint4*>(plane + (size_t)(Hi.i1 * 512 + Wi.i0) * 32);
    const uint4* p11 = reinterpret_cast<const uint4*>(plane + (size_t)(Hi.i1 * 512 + Wi.i1) * 32);
    uint4 L00[4], L01[4], L10[4], L11[4];
#pragma unroll
    for (int g = 0; g < 4; ++g) L00[g] = p00[g];
#pragma unroll
    for (int g = 0; g < 4; ++g) L01[g] = p01[g];
#pragma unroll
    for (int g = 0; g < 4; ++g) L10[g] = p10[g];
#pragma unroll
    for (int g = 0; g < 4; ++g) L11[g] = p11[g];

    const float4* la = reinterpret_cast<const float4*>(line + L.i0 * 32);
    const float4* lb = reinterpret_cast<const float4*>(line + L.i1 * 32);

#pragma unroll
    for (int g = 0; g < 4; ++g) {
        float v00[8], v01[8], v10[8], v11[8];
        unpack8(L00[g], v00); unpack8(L01[g], v01);
        unpack8(L10[g], v10); unpack8(L11[g], v11);
        float4 a0 = la[2 * g], a1 = la[2 * g + 1];
        float4 b0 = lb[2 * g], b1 = lb[2 * g + 1];
        float lv[8];
        lv[0] = a0.x * L.w0 + b0.x * L.w1;
        lv[1] = a0.y * L.w0 + b0.y * L.w1;
        lv[2] = a0.z * L.w0 + b0.z * L.w1;
        lv[3] = a0.w * L.w0 + b0.w * L.w1;
        lv[4] = a1.x * L.w0 + b1.x * L.w1;
        lv[5] = a1.y * L.w0 + b1.y * L.w1;
        lv[6] = a1.z * L.w0 + b1.z * L.w1;
        lv[7] = a1.w * L.w0 + b1.w * L.w1;
#pragma unroll
        for (int i = 0; i < 8; ++i) {
            float bl = v00[i] * w00 + v01[i] * w01 + v10[i] * w10 + v11[i] * w11;
            feat[g * 8 + i] = fmaf(lv[i], bl, feat[g * 8 + i]);
        }
    }
}

// LDS feature staging: per wave 64 rows x 40 halves (80B stride)
#define FROW 40

__global__ __launch_bounds__(256) void tensorf_fused(
    const float* __restrict__ coords,
    const __half* __restrict__ wsp,
    const float* __restrict__ wsl,
    const __half* __restrict__ wsw1,    // [8][64][8] f16 B-fragments
    const float* __restrict__ b1,
    const float* __restrict__ W2,
    const float* __restrict__ b2,
    float* __restrict__ out, int P)
{
    __shared__ __align__(16) __half sfeat[4 * 64 * FROW];   // 20480 B
    int tid  = threadIdx.x;
    int wave = tid >> 6, lane = tid & 63;
    int pbase = blockIdx.x * 256 + wave * 64;
    int p  = pbase + lane;
    int pc = p < P ? p : P - 1;

    float x = coords[3 * pc + 0];
    float y = coords[3 * pc + 1];
    float z = coords[3 * pc + 2];
    LI ax = mk(x), ay = mk(y), az = mk(z);
    const __half* pXY = wsp;                  // H from y, W from x
    const __half* pYZ = wsp + 8388608u;       // H from z, W from y
    const __half* pXZ = wsp + 16777216u;      // H from z, W from x
    const float* lX = wsl;
    const float* lY = wsl + 16384;
    const float* lZ = wsl + 32768;

    float feat[32];
#pragma unroll
    for (int i = 0; i < 32; ++i) feat[i] = 0.f;

    // features = x_embed*yz + y_embed*xz + z_embed*xy
    plane_acc(pYZ, az, ay, lX, ax, feat);   // H=z, W=y, line x
    plane_acc(pXZ, az, ax, lY, ay, feat);   // H=z, W=x, line y
    plane_acc(pXY, ay, ax, lZ, az, feat);   // H=y, W=x, line z

#pragma unroll
    for (int g = 0; g < 4; ++g) {
        F16x8U fu;
#pragma unroll
        for (int i = 0; i < 8; ++i) fu.v[i] = (_Float16)feat[g * 8 + i];
        *reinterpret_cast<uint4*>(sfeat + tid * FROW + g * 8) = fu.u;
    }
    __syncthreads();

    // B fragments (W1), all 8 N-tiles
    f16x8 Bf[8];
#pragma unroll
    for (int t = 0; t < 8; ++t)
        Bf[t] = *reinterpret_cast<const f16x8*>(wsw1 + (t * 64 + lane) * 8);

    // A fragments: 4 M-tiles of this wave's 64 points
    const __half* wb = sfeat + wave * 64 * FROW;
    f16x8 Af[4];
#pragma unroll
    for (int m = 0; m < 4; ++m)
        Af[m] = *reinterpret_cast<const f16x8*>(
            wb + (m * 16 + (lane & 15)) * FROW + (lane >> 4) * 8);

    int nlane = lane & 15;
    f32x4 part[4];
#pragma unroll
    for (int m = 0; m < 4; ++m) part[m] = (f32x4)0.f;

#pragma unroll
    for (int t = 0; t < 8; ++t) {
        float bb  = b1[t * 16 + nlane];
        float w2t = W2[t * 16 + nlane];
        f32x4 cin = { bb, bb, bb, bb };
#pragma unroll
        for (int m = 0; m < 4; ++m) {
            f32x4 acc = __builtin_amdgcn_mfma_f32_16x16x32_f16(Af[m], Bf[t], cin, 0, 0, 0);
#pragma unroll
            for (int r = 0; r < 4; ++r) {
                float h = fmaxf(acc[r], 0.f);
                part[m][r] = fmaf(h, w2t, part[m][r]);
            }
        }
    }

    // reduce across the 16 lanes of each row group (xor 1,2,4,8)
#pragma unroll
    for (int mask = 1; mask < 16; mask <<= 1) {
#pragma unroll
        for (int m = 0; m < 4; ++m) {
#pragma unroll
            for (int r = 0; r < 4; ++r)
                part[m][r] += __shfl_xor(part[m][r], mask, 64);
        }
    }

    // write: row = m*16 + (lane>>4)*4 + r ; lanes nlane<4 write element r=nlane
    float b2v = b2[0];
    if (nlane < 4) {
        int g = lane >> 4;
#pragma unroll
        for (int m = 0; m < 4; ++m) {
            float v = (nlane == 0) ? part[m][0] :
                      (nlane == 1) ? part[m][1] :
                      (nlane == 2) ? part[m][2] : part[m][3];
            int op = pbase + m * 16 + g * 4 + nlane;
            if (op < P) out[op] = v + b2v;
        }
    }
}

extern "C" void kernel_launch(void* const* d_in, const int* in_sizes, int n_in,
                              void* d_out, int out_size, void* d_ws, size_t ws_size,
                              hipStream_t stream)
{
    const float* coords   = (const float*)d_in[0];
    const float* line_x   = (const float*)d_in[1];
    const float* line_y   = (const float*)d_in[2];
    const float* line_z   = (const float*)d_in[3];
    const float* plane_xy = (const float*)d_in[4];
    const float* plane_yz = (const float*)d_in[5];
    const float* plane_xz = (const float*)d_in[6];
    const float* W1 = (const float*)d_in[7];
    const float* b1 = (const float*)d_in[8];
    const float* W2 = (const float*)d_in[9];
    const float* b2 = (const float*)d_in[10];
    int P = in_sizes[0] / 3;

    const size_t off_lines = 3ull * PLANE_HALVES * 2ull;             // 50331648
    const size_t off_w1    = off_lines + 3ull * 512ull * 32ull * 4ull;
    const size_t need      = off_w1 + 8ull * 64ull * 8ull * 2ull;    // +8 KB

    if (ws_size < need) return;

    __half* wsp  = (__half*)d_ws;
    float*  wsl  = (float*)((char*)d_ws + off_lines);
    __half* wsw1 = (__half*)((char*)d_ws + off_w1);

    tp_planes<<<3072, 256, 0, stream>>>(plane_xy, plane_yz, plane_xz, wsp);
    tp_lines<<<192, 256, 0, stream>>>(line_x, line_y, line_z, wsl);
    pack_w1<<<2, 256, 0, stream>>>(W1, wsw1);

    int grid = (P + 255) / 256;
    tensorf_fused<<<grid, 256, 0, stream>>>(coords, wsp, wsl, wsw1,
                                            b1, W2, b2, (float*)d_out, P);
}

// Round 6
// 469.721 us; speedup vs baseline: 1.6030x; 1.1331x over previous
//
#include <hip/hip_runtime.h>
#include <hip/hip_fp16.h>
#include <stdint.h>

#define PLANE_HALVES (512u * 512u * 32u)   // 8388608 halves = 16 MB per plane
#define NCELL 32768                        // 32^3 morton cells

typedef _Float16 f16x8 __attribute__((ext_vector_type(8)));
typedef float    f32x4 __attribute__((ext_vector_type(4)));

union F16x8U { f16x8 v; uint4 u; };

// ---------------- transpose planes [C=32][512][512] f32 -> [512][512][32] f16 ----
__global__ __launch_bounds__(256) void tp_planes(
    const float* __restrict__ pxy,
    const float* __restrict__ pyz,
    const float* __restrict__ pxz,
    __half* __restrict__ ws)
{
    unsigned bid = blockIdx.x;          // 3 * 512 * 2 = 3072 blocks
    unsigned hb = bid & 1u;             // x half
    unsigned y  = (bid >> 1) & 511u;
    unsigned p  = bid >> 10;            // 0..2
    const float* __restrict__ src = (p == 0) ? pxy : (p == 1) ? pyz : pxz;
    unsigned t  = threadIdx.x;
    unsigned cg = t & 3u;               // channel group of 8
    unsigned xq = t >> 2;               // 0..63
    unsigned x  = hb * 256u + xq * 4u;
    unsigned c0 = cg * 8u;
    float4 v[8];
#pragma unroll
    for (int i = 0; i < 8; ++i)
        v[i] = *reinterpret_cast<const float4*>(
            src + (size_t)(c0 + i) * 262144u + y * 512u + x);
#pragma unroll
    for (int j = 0; j < 4; ++j) {
        __half2 h[4];
#pragma unroll
        for (int i = 0; i < 4; ++i) {
            float a = reinterpret_cast<const float*>(&v[2 * i])[j];
            float b = reinterpret_cast<const float*>(&v[2 * i + 1])[j];
            h[i] = __floats2half2_rn(a, b);
        }
        __half* dst = ws + (size_t)p * PLANE_HALVES +
                      (size_t)(y * 512u + x + j) * 32u + c0;
        *reinterpret_cast<uint4*>(dst) = *reinterpret_cast<const uint4*>(h);
    }
}

// ---------------- transpose lines [C=32][512][1] f32 -> [512][32] f32 ------------
__global__ __launch_bounds__(256) void tp_lines(
    const float* __restrict__ lx, const float* __restrict__ ly,
    const float* __restrict__ lz, float* __restrict__ wl)
{
    int e = blockIdx.x * 256 + threadIdx.x;   // 3*512*32 = 49152
    int l = e >> 14;
    int r = e & 16383;
    int h = r >> 5;
    int c = r & 31;
    const float* src = (l == 0) ? lx : (l == 1) ? ly : lz;
    wl[e] = src[c * 512 + h];
}

// ---------------- pack W1 [32][128] f32 into MFMA B-fragments f16 ----------------
// layout: [tile t=0..7][lane L=0..63][j=0..7], elem = W1[k=(L>>4)*8+j][n=t*16+(L&15)]
__global__ __launch_bounds__(256) void pack_w1(
    const float* __restrict__ W1, __half* __restrict__ w)
{
    int tid = blockIdx.x * 256 + threadIdx.x;   // 512 total
    if (tid >= 512) return;
    int t = tid >> 6, L = tid & 63;
    int n  = t * 16 + (L & 15);
    int kg = L >> 4;
    __half h[8];
#pragma unroll
    for (int j = 0; j < 8; ++j)
        h[j] = __float2half(W1[(kg * 8 + j) * 128 + n]);
    *reinterpret_cast<uint4*>(w + tid * 8) = *reinterpret_cast<const uint4*>(h);
}

// ---------------- morton sort ----------------------------------------------------
__device__ inline unsigned spread5(unsigned v) {
    v &= 0x1Fu;
    v = (v | (v << 8)) & 0x100Fu;
    v = (v | (v << 4)) & 0x10C3u;
    v = (v | (v << 2)) & 0x1249u;
    return v;
}

__device__ inline unsigned morton_key(float x, float y, float z) {
    int cx = (int)((x + 1.0f) * 16.0f);
    int cy = (int)((y + 1.0f) * 16.0f);
    int cz = (int)((z + 1.0f) * 16.0f);
    cx = cx < 0 ? 0 : (cx > 31 ? 31 : cx);
    cy = cy < 0 ? 0 : (cy > 31 ? 31 : cy);
    cz = cz < 0 ? 0 : (cz > 31 ? 31 : cz);
    return spread5((unsigned)cx) | (spread5((unsigned)cy) << 1) |
           (spread5((unsigned)cz) << 2);
}

__global__ __launch_bounds__(256) void hist_k(
    const float* __restrict__ coords, unsigned* __restrict__ hist, int P)
{
    int p = blockIdx.x * 256 + threadIdx.x;
    if (p < P) {
        float x = coords[3 * p + 0];
        float y = coords[3 * p + 1];
        float z = coords[3 * p + 2];
        atomicAdd(&hist[morton_key(x, y, z)], 1u);
    }
}

// single block, 1024 threads: in-place exclusive scan over 32768 bins
__global__ __launch_bounds__(1024) void scan_k(unsigned* __restrict__ hist)
{
    __shared__ unsigned part[1024];
    int t = threadIdx.x;
    unsigned c[32];
    unsigned s = 0;
#pragma unroll
    for (int i = 0; i < 32; ++i) { c[i] = hist[t * 32 + i]; s += c[i]; }
    part[t] = s;
    __syncthreads();
    for (int off = 1; off < 1024; off <<= 1) {
        unsigned v = (t >= off) ? part[t - off] : 0u;
        __syncthreads();
        part[t] += v;
        __syncthreads();
    }
    unsigned run = (t == 0) ? 0u : part[t - 1];
#pragma unroll
    for (int i = 0; i < 32; ++i) {
        hist[t * 32 + i] = run;
        run += c[i];
    }
}

__global__ __launch_bounds__(256) void scatter_k(
    const float* __restrict__ coords, unsigned* __restrict__ offs,
    float4* __restrict__ sorted, int P)
{
    int p = blockIdx.x * 256 + threadIdx.x;
    if (p < P) {
        float x = coords[3 * p + 0];
        float y = coords[3 * p + 1];
        float z = coords[3 * p + 2];
        unsigned slot = atomicAdd(&offs[morton_key(x, y, z)], 1u);
        sorted[slot] = make_float4(x, y, z, __int_as_float(p));
    }
}

// ---------------- fused sample + MFMA MLP ----------------------------------------
struct LI { int i0, i1; float w0, w1; };

__device__ inline LI mk(float g) {
    float t = (g + 1.0f) * 0.5f * 511.0f;
    float f = floorf(t);
    LI r;
    r.w1 = t - f;
    r.w0 = 1.0f - r.w1;
    int i0 = (int)f;
    i0 = i0 < 0 ? 0 : (i0 > 511 ? 511 : i0);
    r.i0 = i0;
    r.i1 = i0 < 511 ? i0 + 1 : 511;   // if i1 clamped, w1==0 -> matches zero-pad
    return r;
}

__device__ inline void unpack8(const uint4& u, float o[8]) {
    __half2 h0 = *reinterpret_cast<const __half2*>(&u.x);
    __half2 h1 = *reinterpret_cast<const __half2*>(&u.y);
    __half2 h2 = *reinterpret_cast<const __half2*>(&u.z);
    __half2 h3 = *reinterpret_cast<const __half2*>(&u.w);
    float2 f0 = __half22float2(h0), f1 = __half22float2(h1);
    float2 f2 = __half22float2(h2), f3 = __half22float2(h3);
    o[0] = f0.x; o[1] = f0.y; o[2] = f1.x; o[3] = f1.y;
    o[4] = f2.x; o[5] = f2.y; o[6] = f3.x; o[7] = f3.y;
}

// One plane: fetch 4 full 64B corner lines, lerp all 32 channels,
// feat[c] += linevals[c] * bilerp[c].  line is [512][32] f32 (cache-hot).
__device__ inline void plane_acc(const __half* __restrict__ plane,
                                 const LI& Hi, const LI& Wi,
                                 const float* __restrict__ line, const LI& L,
                                 float feat[32]) {
    float w00 = Hi.w0 * Wi.w0, w01 = Hi.w0 * Wi.w1;
    float w10 = Hi.w1 * Wi.w0, w11 = Hi.w1 * Wi.w1;
    const uint4* p00 = reinterpret_cast<const uint4*>(plane + (size_t)(Hi.i0 * 512 + Wi.i0) * 32);
    const uint4* p01 = reinterpret_cast<const uint4*>(plane + (size_t)(Hi.i0 * 512 + Wi.i1) * 32);
    const uint4* p10 = reinterpret_cast<const uint4*>(plane + (size_t)(Hi.i1 * 512 + Wi.i0) * 32);
    const uint4* p11 = reinterpret_cast<const uint4*>(plane + (size_t)(Hi.i1 * 512 + Wi.i1) * 32);
    uint4 L00[4], L01[4], L10[4], L11[4];
#pragma unroll
    for (int g = 0; g < 4; ++g) L00[g] = p00[g];
#pragma unroll
    for (int g = 0; g < 4; ++g) L01[g] = p01[g];
#pragma unroll
    for (int g = 0; g < 4; ++g) L10[g] = p10[g];
#pragma unroll
    for (int g = 0; g < 4; ++g) L11[g] = p11[g];

    const float4* la = reinterpret_cast<const float4*>(line + L.i0 * 32);
    const float4* lb = reinterpret_cast<const float4*>(line + L.i1 * 32);

#pragma unroll
    for (int g = 0; g < 4; ++g) {
        float v00[8], v01[8], v10[8], v11[8];
        unpack8(L00[g], v00); unpack8(L01[g], v01);
        unpack8(L10[g], v10); unpack8(L11[g], v11);
        float4 a0 = la[2 * g], a1 = la[2 * g + 1];
        float4 b0 = lb[2 * g], b1 = lb[2 * g + 1];
        float lv[8];
        lv[0] = a0.x * L.w0 + b0.x * L.w1;
        lv[1] = a0.y * L.w0 + b0.y * L.w1;
        lv[2] = a0.z * L.w0 + b0.z * L.w1;
        lv[3] = a0.w * L.w0 + b0.w * L.w1;
        lv[4] = a1.x * L.w0 + b1.x * L.w1;
        lv[5] = a1.y * L.w0 + b1.y * L.w1;
        lv[6] = a1.z * L.w0 + b1.z * L.w1;
        lv[7] = a1.w * L.w0 + b1.w * L.w1;
#pragma unroll
        for (int i = 0; i < 8; ++i) {
            float bl = v00[i] * w00 + v01[i] * w01 + v10[i] * w10 + v11[i] * w11;
            feat[g * 8 + i] = fmaf(lv[i], bl, feat[g * 8 + i]);
        }
    }
}

// LDS feature staging: per wave 64 rows x 40 halves (80B stride).
// halves 0..31 = features; halves 32..33 = original point index (int).
#define FROW 40

template <bool SORTED>
__global__ __launch_bounds__(256) void tensorf_fused(
    const float* __restrict__ coords,
    const float4* __restrict__ sorted,
    const __half* __restrict__ wsp,
    const float* __restrict__ wsl,
    const __half* __restrict__ wsw1,    // [8][64][8] f16 B-fragments
    const float* __restrict__ b1,
    const float* __restrict__ W2,
    const float* __restrict__ b2,
    float* __restrict__ out, int P)
{
    __shared__ __align__(16) __half sfeat[4 * 64 * FROW];   // 20480 B
    int tid  = threadIdx.x;
    int wave = tid >> 6, lane = tid & 63;
    int pbase = blockIdx.x * 256 + wave * 64;
    int p  = pbase + lane;
    int pc = p < P ? p : P - 1;

    float x, y, z;
    int oidx_self;
    if (SORTED) {
        float4 cp = sorted[pc];
        x = cp.x; y = cp.y; z = cp.z;
        oidx_self = __float_as_int(cp.w);
    } else {
        x = coords[3 * pc + 0];
        y = coords[3 * pc + 1];
        z = coords[3 * pc + 2];
        oidx_self = pc;
    }
    LI ax = mk(x), ay = mk(y), az = mk(z);
    const __half* pXY = wsp;                  // H from y, W from x
    const __half* pYZ = wsp + 8388608u;       // H from z, W from y
    const __half* pXZ = wsp + 16777216u;      // H from z, W from x
    const float* lX = wsl;
    const float* lY = wsl + 16384;
    const float* lZ = wsl + 32768;

    float feat[32];
#pragma unroll
    for (int i = 0; i < 32; ++i) feat[i] = 0.f;

    // features = x_embed*yz + y_embed*xz + z_embed*xy
    plane_acc(pYZ, az, ay, lX, ax, feat);   // H=z, W=y, line x
    plane_acc(pXZ, az, ax, lY, ay, feat);   // H=z, W=x, line y
    plane_acc(pXY, ay, ax, lZ, az, feat);   // H=y, W=x, line z

#pragma unroll
    for (int g = 0; g < 4; ++g) {
        F16x8U fu;
#pragma unroll
        for (int i = 0; i < 8; ++i) fu.v[i] = (_Float16)feat[g * 8 + i];
        *reinterpret_cast<uint4*>(sfeat + tid * FROW + g * 8) = fu.u;
    }
    // stash original index in the spare bytes of this point's LDS row
    // (all 64 lanes execute this -> no divergent cross-lane hazards)
    *reinterpret_cast<int*>(sfeat + tid * FROW + 32) = oidx_self;
    __syncthreads();

    // B fragments (W1), all 8 N-tiles
    f16x8 Bf[8];
#pragma unroll
    for (int t = 0; t < 8; ++t)
        Bf[t] = *reinterpret_cast<const f16x8*>(wsw1 + (t * 64 + lane) * 8);

    // A fragments: 4 M-tiles of this wave's 64 points
    const __half* wb = sfeat + wave * 64 * FROW;
    f16x8 Af[4];
#pragma unroll
    for (int m = 0; m < 4; ++m)
        Af[m] = *reinterpret_cast<const f16x8*>(
            wb + (m * 16 + (lane & 15)) * FROW + (lane >> 4) * 8);

    int nlane = lane & 15;
    f32x4 part[4];
#pragma unroll
    for (int m = 0; m < 4; ++m) part[m] = (f32x4)0.f;

#pragma unroll
    for (int t = 0; t < 8; ++t) {
        float bb  = b1[t * 16 + nlane];
        float w2t = W2[t * 16 + nlane];
        f32x4 cin = { bb, bb, bb, bb };
#pragma unroll
        for (int m = 0; m < 4; ++m) {
            f32x4 acc = __builtin_amdgcn_mfma_f32_16x16x32_f16(Af[m], Bf[t], cin, 0, 0, 0);
#pragma unroll
            for (int r = 0; r < 4; ++r) {
                float h = fmaxf(acc[r], 0.f);
                part[m][r] = fmaf(h, w2t, part[m][r]);
            }
        }
    }

    // reduce across the 16 lanes of each row group (xor 1,2,4,8)
#pragma unroll
    for (int mask = 1; mask < 16; mask <<= 1) {
#pragma unroll
        for (int m = 0; m < 4; ++m) {
#pragma unroll
            for (int r = 0; r < 4; ++r)
                part[m][r] += __shfl_xor(part[m][r], mask, 64);
        }
    }

    // write: row = m*16 + (lane>>4)*4 + r ; lanes nlane<4 write element r=nlane.
    // original index fetched from LDS (safe under divergence).
    float b2v = b2[0];
    if (nlane < 4) {
        int g = lane >> 4;
#pragma unroll
        for (int m = 0; m < 4; ++m) {
            float v = (nlane == 0) ? part[m][0] :
                      (nlane == 1) ? part[m][1] :
                      (nlane == 2) ? part[m][2] : part[m][3];
            int src = m * 16 + g * 4 + nlane;   // row within wave
            int oidx = *reinterpret_cast<const int*>(wb + src * FROW + 32);
            if (pbase + src < P) out[oidx] = v + b2v;
        }
    }
}

extern "C" void kernel_launch(void* const* d_in, const int* in_sizes, int n_in,
                              void* d_out, int out_size, void* d_ws, size_t ws_size,
                              hipStream_t stream)
{
    const float* coords   = (const float*)d_in[0];
    const float* line_x   = (const float*)d_in[1];
    const float* line_y   = (const float*)d_in[2];
    const float* line_z   = (const float*)d_in[3];
    const float* plane_xy = (const float*)d_in[4];
    const float* plane_yz = (const float*)d_in[5];
    const float* plane_xz = (const float*)d_in[6];
    const float* W1 = (const float*)d_in[7];
    const float* b1 = (const float*)d_in[8];
    const float* W2 = (const float*)d_in[9];
    const float* b2 = (const float*)d_in[10];
    int P = in_sizes[0] / 3;

    const size_t off_lines  = 3ull * PLANE_HALVES * 2ull;            // 48 MB
    const size_t off_w1     = off_lines + 3ull * 512ull * 32ull * 4ull;
    const size_t off_hist   = off_w1 + 8ull * 64ull * 8ull * 2ull;
    const size_t off_sorted = off_hist + (size_t)NCELL * 4ull;       // 256-aligned
    const size_t need_base   = off_hist;
    const size_t need_sorted = off_sorted + (size_t)P * 16ull;

    if (ws_size < need_base) return;

    __half*   wsp    = (__half*)d_ws;
    float*    wsl    = (float*)((char*)d_ws + off_lines);
    __half*   wsw1   = (__half*)((char*)d_ws + off_w1);
    unsigned* hist   = (unsigned*)((char*)d_ws + off_hist);
    float4*   sorted = (float4*)((char*)d_ws + off_sorted);

    tp_planes<<<3072, 256, 0, stream>>>(plane_xy, plane_yz, plane_xz, wsp);
    tp_lines<<<192, 256, 0, stream>>>(line_x, line_y, line_z, wsl);
    pack_w1<<<2, 256, 0, stream>>>(W1, wsw1);

    int grid = (P + 255) / 256;
    if (ws_size >= need_sorted) {
        hipMemsetAsync(hist, 0, (size_t)NCELL * 4ull, stream);
        hist_k<<<grid, 256, 0, stream>>>(coords, hist, P);
        scan_k<<<1, 1024, 0, stream>>>(hist);
        scatter_k<<<grid, 256, 0, stream>>>(coords, hist, sorted, P);
        tensorf_fused<true><<<grid, 256, 0, stream>>>(
            coords, sorted, wsp, wsl, wsw1, b1, W2, b2, (float*)d_out, P);
    } else {
        tensorf_fused<false><<<grid, 256, 0, stream>>>(
            coords, nullptr, wsp, wsl, wsw1, b1, W2, b2, (float*)d_out, P);
    }
}